// Round 13
// baseline (249.893 us; speedup 1.0000x reference)
//
#include <hip/hip_runtime.h>
#include <stdint.h>
#include <math.h>

#define B_ 4
#define S_ 2048
#define C_ 256
#define H_ 8

typedef short bf16x8 __attribute__((ext_vector_type(8)));
typedef float f32x4 __attribute__((ext_vector_type(4)));
typedef float f32x16 __attribute__((ext_vector_type(16)));

static __device__ __forceinline__ short f2bf(float f) {
  uint32_t u = __float_as_uint(f);
  u = (u + 0x7fffu + ((u >> 16) & 1u)) >> 16;
  return (short)u;
}

static __device__ __forceinline__ int cvtpk(float lo, float hi) {
  int r;
  asm("v_cvt_pk_bf16_f32 %0, %1, %2" : "=v"(r) : "v"(lo), "v"(hi));
  return r;
}

static __device__ __forceinline__ bf16x8 pack4(int a, int b, int c, int d) {
  union { int i[4]; bf16x8 v; } u;
  u.i[0] = a; u.i[1] = b; u.i[2] = c; u.i[3] = d;
  return u.v;
}

static __device__ __forceinline__ void gld16(const void* g, void* l) {
  __builtin_amdgcn_global_load_lds(
      (const __attribute__((address_space(1))) uint32_t*)g,
      (__attribute__((address_space(3))) uint32_t*)l, 16, 0, 0);
}

// ---------------- elementwise convert fp32 -> bf16 ----------------
__global__ void cvt_f32_bf16(const float* __restrict__ in, short* __restrict__ out, int n) {
  int i = (blockIdx.x * 256 + threadIdx.x) * 8;
  if (i >= n) return;
  float4 a = *(const float4*)(in + i);
  float4 b = *(const float4*)(in + i + 4);
  bf16x8 r;
  r[0] = f2bf(a.x); r[1] = f2bf(a.y); r[2] = f2bf(a.z); r[3] = f2bf(a.w);
  r[4] = f2bf(b.x); r[5] = f2bf(b.y); r[6] = f2bf(b.z); r[7] = f2bf(b.w);
  *(bf16x8*)(out + i) = r;
}

// ---------------- fused transpose-convert for all 4 weights ----------------
__global__ void transpose_cvt4(const float* __restrict__ Wq, const float* __restrict__ Wk,
                               const float* __restrict__ Wv, const float* __restrict__ Wo,
                               short* __restrict__ WqT, short* __restrict__ WkT,
                               short* __restrict__ WvT, short* __restrict__ WoT) {
  __shared__ float t[32][33];
  int bid = blockIdx.x;            // 0..2047
  int which = bid >> 9, rem = bid & 511;
  const float* in; short* outp; int R, Cc, bx, by;
  if (which < 3) {
    R = 256; Cc = 2048; bx = rem & 63; by = rem >> 6;
    in = which == 0 ? Wq : (which == 1 ? Wk : Wv);
    outp = which == 0 ? WqT : (which == 1 ? WkT : WvT);
  } else {
    R = 2048; Cc = 256; bx = rem & 7; by = rem >> 3;
    in = Wo; outp = WoT;
  }
  int cb = bx * 32, rb = by * 32;
  int tr = threadIdx.x >> 5;   // 0..7
  int tc = threadIdx.x & 31;
#pragma unroll
  for (int i = 0; i < 4; i++)
    t[tr + i * 8][tc] = in[(size_t)(rb + tr + i * 8) * Cc + cb + tc];
  __syncthreads();
#pragma unroll
  for (int i = 0; i < 4; i++)
    outp[(size_t)(cb + tr + i * 8) * R + rb + tc] = f2bf(t[tc][tr + i * 8]);
}

// ---------------- GEMM: A (MxK bf16) * Bt^T (Bt is NxK bf16) + bias ----------
// MODE 0: out bf16 (B,H,S,C) row-major, val=(acc+bias)*scale           (Q)
// MODE 3: out bf16 PACKED-K tiles, val=(acc+bias)*scale                (K)
// MODE 1: out bf16 PACKED-V tiles, val=acc+bias                        (V)
// MODE 4: split-K partial (z = K-chunk of 512), out f32 parts, no bias (out-proj)
template<int MODE>
__global__ void __launch_bounds__(256, 2) gemm_k(
    const short* __restrict__ A, const short* __restrict__ Bt,
    const float* __restrict__ bias, float scale, void* __restrict__ out,
    int M, int N, int K) {
  __shared__ char smem[36864];
  const int tid = threadIdx.x;
  const int l = tid & 63;
  const int w = tid >> 6;
  const int wr = w >> 1, wc = w & 1;
  const int mbase = blockIdx.y * 128;
  const int nbase = blockIdx.x * 128;

  const f32x4 fzero = {0.f, 0.f, 0.f, 0.f};
  f32x4 acc[4][4];
#pragma unroll
  for (int i = 0; i < 4; i++)
#pragma unroll
    for (int j = 0; j < 4; j++) acc[i][j] = fzero;

  const int kt0 = (MODE == 4) ? blockIdx.z * 16 : 0;
  const int nkt = (MODE == 4) ? 16 : (K >> 5);
  for (int kt = kt0; kt < kt0 + nkt; ++kt) {
#pragma unroll
    for (int c = 0; c < 2; c++) {
      int row = c * 64 + w * 16 + (l >> 2);
      const short* ga = A + (size_t)(mbase + row) * K + kt * 32 + (l & 3) * 8;
      gld16(ga, smem + (c * 4 + w) * 1024);
      const short* gb = Bt + (size_t)(nbase + row) * K + kt * 32 + (l & 3) * 8;
      gld16(gb, smem + 8192 + (c * 4 + w) * 1024);
    }
    __syncthreads();
    bf16x8 af[4], bf[4];
#pragma unroll
    for (int mf = 0; mf < 4; mf++)
      af[mf] = *(const bf16x8*)(smem + (wr * 64 + mf * 16 + (l & 15)) * 64 + ((l >> 4) << 4));
#pragma unroll
    for (int nf = 0; nf < 4; nf++)
      bf[nf] = *(const bf16x8*)(smem + 8192 + (wc * 64 + nf * 16 + (l & 15)) * 64 + ((l >> 4) << 4));
#pragma unroll
    for (int mf = 0; mf < 4; mf++)
#pragma unroll
      for (int nf = 0; nf < 4; nf++)
        acc[mf][nf] = __builtin_amdgcn_mfma_f32_16x16x32_bf16(af[mf], bf[nf], acc[mf][nf], 0, 0, 0);
    __syncthreads();
  }

  if (MODE == 0) {
#pragma unroll
    for (int mf = 0; mf < 4; mf++)
#pragma unroll
      for (int nf = 0; nf < 4; nf++)
#pragma unroll
        for (int i = 0; i < 4; i++) {
          int m = mbase + wr * 64 + mf * 16 + (l >> 4) * 4 + i;
          int n = nbase + wc * 64 + nf * 16 + (l & 15);
          float v = (acc[mf][nf][i] + bias[n]) * scale;
          int b = m >> 11, s = m & 2047;
          int h = n >> 8, d = n & 255;
          ((short*)out)[((size_t)(b * H_ + h) * S_ + s) * C_ + d] = f2bf(v);
        }
  } else if (MODE == 4) {
    float* pout = (float*)out + (size_t)blockIdx.z * M * N;
#pragma unroll
    for (int mf = 0; mf < 4; mf++)
#pragma unroll
      for (int nf = 0; nf < 4; nf++)
#pragma unroll
        for (int i = 0; i < 4; i++) {
          int m = mbase + wr * 64 + mf * 16 + (l >> 4) * 4 + i;
          int n = nbase + wc * 64 + nf * 16 + (l & 15);
          pout[(size_t)m * N + n] = acc[mf][nf][i];
        }
  } else {
    // MODE 1 / MODE 3: bounce through T[128][136], then packed-tile emit
    short* T = (short*)smem;
#pragma unroll
    for (int mf = 0; mf < 4; mf++)
#pragma unroll
      for (int nf = 0; nf < 4; nf++)
#pragma unroll
        for (int i = 0; i < 4; i++) {
          int ml = wr * 64 + mf * 16 + (l >> 4) * 4 + i;
          int nl = wc * 64 + nf * 16 + (l & 15);
          float v = (acc[mf][nf][i] + bias[nbase + nl]) * scale;
          T[ml * 136 + nl] = f2bf(v);
        }
    __syncthreads();
    int b = mbase >> 11, s0 = mbase & 2047;
    int h = nbase >> 8;
    int kt0e = s0 >> 5;
    char* hb = (char*)out + ((size_t)(b * H_ + h) << 20);  // 1 MB per head
    if (MODE == 3) {
#pragma unroll
      for (int i2 = 0; i2 < 8; i2++) {
        int sid = tid * 8 + i2;            // 0..2047
        int kt_l = sid >> 9, rem = sid & 511;
        int ksl = rem >> 6, lane2 = rem & 63;
        int tok = kt_l * 32 + (lane2 & 31);
        int dl = ksl * 16 + ((lane2 >> 5) << 3);
        bf16x8 v = *(const bf16x8*)&T[tok * 136 + dl];
        int ksg = ((nbase & 255) >> 4) + ksl;
        *(bf16x8*)(hb + ((size_t)(kt0e + kt_l) << 14) + ((ksg * 64 + lane2) << 4)) = v;
      }
    } else {
#pragma unroll
      for (int i2 = 0; i2 < 8; i2++) {
        int sid = tid * 8 + i2;
        int kt_l = sid >> 9, rem = sid & 511;
        int dtl = rem >> 7, kb = (rem >> 6) & 1, lane2 = rem & 63;
        int dl = dtl * 32 + (lane2 & 31);
        int k0 = kt_l * 32 + kb * 16 + ((lane2 >> 5) << 3);
        bf16x8 pk;
#pragma unroll
        for (int j = 0; j < 8; j++) pk[j] = T[(k0 + j) * 136 + dl];
        int dtg = ((nbase & 255) >> 5) + dtl;
        *(bf16x8*)(hb + ((size_t)(kt0e + kt_l) << 14) + (((dtg * 2 + kb) * 64 + lane2) << 4)) = pk;
      }
    }
  }
}

// ---------------- reduce 4 split-K partials + bias -> fp32 out ---------------
__global__ void reduce4(const float* __restrict__ part, const float* __restrict__ bias,
                        float* __restrict__ out) {
  const int MN = 8192 * 256;
  int i = (blockIdx.x * 256 + threadIdx.x) * 4;
  if (i >= MN) return;
  float4 a = *(const float4*)(part + i);
  float4 b = *(const float4*)(part + MN + i);
  float4 c = *(const float4*)(part + 2 * MN + i);
  float4 d = *(const float4*)(part + 3 * MN + i);
  float4 bs = *(const float4*)(bias + (i & 255));
  float4 r;
  r.x = a.x + b.x + c.x + d.x + bs.x;
  r.y = a.y + b.y + c.y + d.y + bs.y;
  r.z = a.z + b.z + c.z + d.z + bs.z;
  r.w = a.w + b.w + c.w + d.w + bs.w;
  *(float4*)(out + i) = r;
}

// ---------------- flash attention (4 waves, packed K/V, anti-phase) ----------
// grid 512 = 2 blocks/CU (64KB LDS), XCD-chunked; 2 waves/SIMD from DIFFERENT
// blocks. ANTI-PHASE: co-resident blocks (i, i+256 under round-robin dispatch)
// are offset by ~half an iteration via s_sleep, so one block's softmax VALU
// co-issues under the other block's MFMA-blocked phase (m114 cross-wave
// overlap). setprio(1) on MFMA clusters stabilizes the split (T5 regime).
// Wave owns 32 q-rows; swapped QK^T + T12 pack; no-max softmax (Q pre-scaled
// by 0.25*log2e). Packed K/V: linear staging, lane-linear conflict-free reads.
// Reg budget: o 128 AGPR + arch ~124 <= 128 (2 waves/SIMD cap) -> no spill.
__global__ void __launch_bounds__(256, 2) attn_k(
    const short* __restrict__ Qg, const char* __restrict__ Kpk,
    const char* __restrict__ Vpk, short* __restrict__ Ag) {
  __shared__ char smem[65536];
  const int tid = threadIdx.x, l = tid & 63, w = tid >> 6;   // w = 0..3
  const int hi = l >> 5;
  const int lq = l & 31;

  // anti-phase offset: second dispatch round sleeps ~2.7K cycles (half iter)
  if ((blockIdx.x >> 8) & 1) __builtin_amdgcn_s_sleep(42);

  const int orig = (blockIdx.x & 7) * 64 + (blockIdx.x >> 3);  // bijective XCD chunk
  const int head = orig >> 4;
  const int qbase = (orig & 15) * 128 + w * 32;

  // Q fragments (B-operand): lane col q = lq, elem j <-> d = ks*16 + hi*8 + j
  bf16x8 qf[16];
  {
    const short* qb = Qg + ((size_t)head * S_ + qbase + lq) * C_;
#pragma unroll
    for (int ks = 0; ks < 16; ks++) {
      qf[ks] = *(const bf16x8*)(qb + ks * 16 + hi * 8);
      asm volatile("" : "+v"(qf[ks]));  // materialize pre-loop
    }
  }

  f32x16 o[8];
#pragma unroll
  for (int dt = 0; dt < 8; dt++)
#pragma unroll
    for (int r = 0; r < 16; r++) o[dt][r] = 0.0f;
  float lrun = 0.0f;

  const char* kpH = Kpk + ((size_t)head << 20);
  const char* vpH = Vpk + ((size_t)head << 20);
  const int vo = tid << 4;        // linear 16B offset, same for src and dest
  const int lo = l << 4;          // lane-linear LDS read offset

  // STAGE tile t into buffer t&1: 8 linear gld16 per thread (4 K + 4 V)
  auto STAGE = [&](int t) {
    char* Kd = smem + (t & 1) * 32768;
    char* Vd = Kd + 16384;
    const char* kq = kpH + ((size_t)t << 14);
    const char* vq = vpH + ((size_t)t << 14);
#pragma unroll
    for (int c = 0; c < 4; c++)
      gld16(kq + c * 4096 + vo, Kd + c * 4096 + vo);
#pragma unroll
    for (int c = 0; c < 4; c++)
      gld16(vq + c * 4096 + vo, Vd + c * 4096 + vo);
  };

  // per-tile compute: QK^T -> exp2 -> T12 pack -> PV (all fragment reads linear)
  auto CALC = [&](int t) {
    const char* Ks = smem + (t & 1) * 32768;
    const char* Vs = Ks + 16384;
    f32x16 st;
#pragma unroll
    for (int r = 0; r < 16; r++) st[r] = 0.0f;
    __builtin_amdgcn_s_setprio(1);
#pragma unroll
    for (int ks = 0; ks < 16; ks++) {
      bf16x8 kf = *(const bf16x8*)(Ks + ks * 1024 + lo);
      st = __builtin_amdgcn_mfma_f32_32x32x16_bf16(kf, qf[ks], st, 0, 0, 0);
    }
    __builtin_amdgcn_s_setprio(0);
#pragma unroll
    for (int r = 0; r < 16; r++) st[r] = exp2f(st[r]);
    {
      float t0 = (st[0] + st[1]) + (st[2] + st[3]);
      float t1 = (st[4] + st[5]) + (st[6] + st[7]);
      float t2 = (st[8] + st[9]) + (st[10] + st[11]);
      float t3 = (st[12] + st[13]) + (st[14] + st[15]);
      lrun += (t0 + t1) + (t2 + t3);
    }
    __builtin_amdgcn_s_setprio(1);
    {
      int a0 = cvtpk(st[0], st[1]), a1 = cvtpk(st[2], st[3]);
      int a2 = cvtpk(st[4], st[5]), a3 = cvtpk(st[6], st[7]);
      auto s0p = __builtin_amdgcn_permlane32_swap(a0, a2, false, false);
      auto s1p = __builtin_amdgcn_permlane32_swap(a1, a3, false, false);
      bf16x8 pf0 = pack4(s0p[0], s1p[0], s0p[1], s1p[1]);  // k 0..15
#pragma unroll
      for (int dt = 0; dt < 8; dt++) {
        bf16x8 v0 = *(const bf16x8*)(Vs + (dt * 2) * 1024 + lo);
        o[dt] = __builtin_amdgcn_mfma_f32_32x32x16_bf16(v0, pf0, o[dt], 0, 0, 0);
      }
    }
    {
      int a4 = cvtpk(st[8], st[9]),   a5 = cvtpk(st[10], st[11]);
      int a6 = cvtpk(st[12], st[13]), a7 = cvtpk(st[14], st[15]);
      auto s2p = __builtin_amdgcn_permlane32_swap(a4, a6, false, false);
      auto s3p = __builtin_amdgcn_permlane32_swap(a5, a7, false, false);
      bf16x8 pf1 = pack4(s2p[0], s3p[0], s2p[1], s3p[1]);  // k 16..31
#pragma unroll
      for (int dt = 0; dt < 8; dt++) {
        bf16x8 v1 = *(const bf16x8*)(Vs + (dt * 2 + 1) * 1024 + lo);
        o[dt] = __builtin_amdgcn_mfma_f32_32x32x16_bf16(v1, pf1, o[dt], 0, 0, 0);
      }
    }
    __builtin_amdgcn_s_setprio(0);
  };

  STAGE(0);

#pragma unroll 1
  for (int t = 0; t < 64; ++t) {
    if (t < 63) {
      STAGE(t + 1);
      asm volatile("s_waitcnt vmcnt(8)" ::: "memory");  // tile t landed; t+1 in flight
    } else {
      asm volatile("s_waitcnt vmcnt(0)" ::: "memory");
    }
    __builtin_amdgcn_s_barrier();   // publish tile t
    CALC(t);
    asm volatile("" ::: "memory");  // pin LDS reads before barrier
    __builtin_amdgcn_s_barrier();   // buf t&1 free for restage at t+1
  }

  // ---- epilogue: finish row sum, normalize, O^T -> LDS (swizzled) -> store
  float lsum = lrun + __shfl_xor(lrun, 32);
  float inv = 1.0f / lsum;
  char* ob = smem + w * 16384;  // per-wave 32 q-rows x 512B
#pragma unroll
  for (int dt = 0; dt < 8; dt++) {
#pragma unroll
    for (int m = 0; m < 4; m++) {
      int lo32 = cvtpk(o[dt][4 * m + 0] * inv, o[dt][4 * m + 1] * inv);
      int hi32 = cvtpk(o[dt][4 * m + 2] * inv, o[dt][4 * m + 3] * inv);
      int cs = (dt * 4 + m) ^ lq;
      int* p = (int*)(ob + lq * 512 + cs * 16 + hi * 8);
      p[0] = lo32; p[1] = hi32;
    }
  }
  int bb = head >> 3, hh = head & 7;
#pragma unroll
  for (int pi = 0; pi < 16; pi++) {
    int qr = pi * 2 + hi;
    bf16x8 v = *(const bf16x8*)(ob + qr * 512 + ((lq ^ qr) << 4));
    size_t g = ((size_t)(bb * S_ + qbase + qr) * (H_ * C_)) + hh * C_ + lq * 8;
    *(bf16x8*)(Ag + g) = v;
  }
}

// ---------------- launch ----------------------------------------------------
extern "C" void kernel_launch(void* const* d_in, const int* in_sizes, int n_in,
                              void* d_out, int out_size, void* d_ws, size_t ws_size,
                              hipStream_t stream) {
  const float* x  = (const float*)d_in[0];
  const float* Wq = (const float*)d_in[1];
  const float* bq = (const float*)d_in[2];
  const float* Wk = (const float*)d_in[3];
  const float* bk = (const float*)d_in[4];
  const float* Wv = (const float*)d_in[5];
  const float* bv = (const float*)d_in[6];
  const float* Wo = (const float*)d_in[7];
  const float* bo = (const float*)d_in[8];

  char* ws = (char*)d_ws;
  short* xb  = (short*)(ws);               //  4 MB
  short* WqT = (short*)(ws + 4194304);     //  1 MB
  short* WkT = (short*)(ws + 5242880);
  short* WvT = (short*)(ws + 6291456);
  short* WoT = (short*)(ws + 7340032);
  short* Qg  = (short*)(ws + 8388608);     // 32 MB (B,H,S,C) row-major
  char*  Kpk = (char*)(ws + 41943040);     // 32 MB packed-K; reused as f32 partials
  char*  Vpk = (char*)(ws + 75497472);     // 32 MB packed-V
  short* Ag  = (short*)(ws + 109051904);   // 32 MB (B,S,H*C)

  cvt_f32_bf16<<<1024, 256, 0, stream>>>(x, xb, 8192 * 256);
  transpose_cvt4<<<2048, 256, 0, stream>>>(Wq, Wk, Wv, Wo, WqT, WkT, WvT, WoT);

  // Q pre-scaled by 256^(-1/4) * log2(e) so attention uses exp2 directly.
  const float scq = 0.25f * 1.44269504088896f;
  const float sck = 0.25f;
  gemm_k<0><<<dim3(16, 64), 256, 0, stream>>>(xb, WqT, bq, scq, Qg, 8192, 2048, 256);
  gemm_k<3><<<dim3(16, 64), 256, 0, stream>>>(xb, WkT, bk, sck, Kpk, 8192, 2048, 256);
  gemm_k<1><<<dim3(16, 64), 256, 0, stream>>>(xb, WvT, bv, 1.0f, Vpk, 8192, 2048, 256);
  attn_k<<<512, 256, 0, stream>>>(Qg, Kpk, Vpk, Ag);
  // out-proj: split-K x4 into retired Kpk buffer (f32 partials), then reduce.
  gemm_k<4><<<dim3(2, 64, 4), 256, 0, stream>>>(Ag, WoT, nullptr, 1.0f, Kpk, 8192, 256, 2048);
  reduce4<<<2048, 256, 0, stream>>>((const float*)Kpk, bo, (float*)d_out);
}

// Round 14
// 231.080 us; speedup vs baseline: 1.0814x; 1.0814x over previous
//
#include <hip/hip_runtime.h>
#include <stdint.h>
#include <math.h>

#define B_ 4
#define S_ 2048
#define C_ 256
#define H_ 8

typedef short bf16x8 __attribute__((ext_vector_type(8)));
typedef float f32x4 __attribute__((ext_vector_type(4)));
typedef float f32x16 __attribute__((ext_vector_type(16)));

static __device__ __forceinline__ short f2bf(float f) {
  uint32_t u = __float_as_uint(f);
  u = (u + 0x7fffu + ((u >> 16) & 1u)) >> 16;
  return (short)u;
}

static __device__ __forceinline__ int cvtpk(float lo, float hi) {
  int r;
  asm("v_cvt_pk_bf16_f32 %0, %1, %2" : "=v"(r) : "v"(lo), "v"(hi));
  return r;
}

static __device__ __forceinline__ bf16x8 pack4(int a, int b, int c, int d) {
  union { int i[4]; bf16x8 v; } u;
  u.i[0] = a; u.i[1] = b; u.i[2] = c; u.i[3] = d;
  return u.v;
}

static __device__ __forceinline__ void gld16(const void* g, void* l) {
  __builtin_amdgcn_global_load_lds(
      (const __attribute__((address_space(1))) uint32_t*)g,
      (__attribute__((address_space(3))) uint32_t*)l, 16, 0, 0);
}

// ---------------- fused prep: x->bf16 cvt (1024 blocks) + 4x weight transpose
__global__ void prep_k(const float* __restrict__ x, short* __restrict__ xb,
                       const float* __restrict__ Wq, const float* __restrict__ Wk,
                       const float* __restrict__ Wv, const float* __restrict__ Wo,
                       short* __restrict__ WqT, short* __restrict__ WkT,
                       short* __restrict__ WvT, short* __restrict__ WoT) {
  int bid = blockIdx.x;
  if (bid < 1024) {
    int i = (bid * 256 + threadIdx.x) * 8;
    float4 a = *(const float4*)(x + i);
    float4 b = *(const float4*)(x + i + 4);
    bf16x8 r;
    r[0] = f2bf(a.x); r[1] = f2bf(a.y); r[2] = f2bf(a.z); r[3] = f2bf(a.w);
    r[4] = f2bf(b.x); r[5] = f2bf(b.y); r[6] = f2bf(b.z); r[7] = f2bf(b.w);
    *(bf16x8*)(xb + i) = r;
    return;
  }
  __shared__ float t[32][33];
  int tbid = bid - 1024;           // 0..2047
  int which = tbid >> 9, rem = tbid & 511;
  const float* in; short* outp; int R, Cc, bx, by;
  if (which < 3) {
    R = 256; Cc = 2048; bx = rem & 63; by = rem >> 6;
    in = which == 0 ? Wq : (which == 1 ? Wk : Wv);
    outp = which == 0 ? WqT : (which == 1 ? WkT : WvT);
  } else {
    R = 2048; Cc = 256; bx = rem & 7; by = rem >> 3;
    in = Wo; outp = WoT;
  }
  int cb = bx * 32, rb = by * 32;
  int tr = threadIdx.x >> 5;
  int tc = threadIdx.x & 31;
#pragma unroll
  for (int i = 0; i < 4; i++)
    t[tr + i * 8][tc] = in[(size_t)(rb + tr + i * 8) * Cc + cb + tc];
  __syncthreads();
#pragma unroll
  for (int i = 0; i < 4; i++)
    outp[(size_t)(cb + tr + i * 8) * R + rb + tc] = f2bf(t[tc][tr + i * 8]);
}

// ---------------- fused QKV GEMM: one launch, z = {0:Q, 1:K, 2:V} ------------
// A (8192x256 bf16) * W^T (2048x256 bf16) + bias. Epilogues:
// z=0: Q row-major (B,H,S,C), val=(acc+bias)*scq (scq folds log2e)
// z=1: K packed-fragment tiles (1MB/head), val=(acc+bias)*0.25
// z=2: V packed-fragment tiles, val=acc+bias
__global__ void __launch_bounds__(256, 2) gemm_qkv(
    const short* __restrict__ A,
    const short* __restrict__ WqT, const short* __restrict__ WkT,
    const short* __restrict__ WvT,
    const float* __restrict__ bq, const float* __restrict__ bk,
    const float* __restrict__ bv,
    short* __restrict__ Qg, char* __restrict__ Kpk, char* __restrict__ Vpk) {
  __shared__ char smem[36864];
  const int tid = threadIdx.x;
  const int l = tid & 63;
  const int w = tid >> 6;
  const int wr = w >> 1, wc = w & 1;
  const int mbase = blockIdx.y * 128;
  const int nbase = blockIdx.x * 128;
  const int z = blockIdx.z;

  const short* Bt = z == 0 ? WqT : (z == 1 ? WkT : WvT);
  const float* bias = z == 0 ? bq : (z == 1 ? bk : bv);
  const float scale = z == 0 ? 0.25f * 1.44269504088896f : (z == 1 ? 0.25f : 1.0f);

  const f32x4 fzero = {0.f, 0.f, 0.f, 0.f};
  f32x4 acc[4][4];
#pragma unroll
  for (int i = 0; i < 4; i++)
#pragma unroll
    for (int j = 0; j < 4; j++) acc[i][j] = fzero;

  for (int kt = 0; kt < 8; ++kt) {
#pragma unroll
    for (int c = 0; c < 2; c++) {
      int row = c * 64 + w * 16 + (l >> 2);
      const short* ga = A + (size_t)(mbase + row) * 256 + kt * 32 + (l & 3) * 8;
      gld16(ga, smem + (c * 4 + w) * 1024);
      const short* gb = Bt + (size_t)(nbase + row) * 256 + kt * 32 + (l & 3) * 8;
      gld16(gb, smem + 8192 + (c * 4 + w) * 1024);
    }
    __syncthreads();
    bf16x8 af[4], bf[4];
#pragma unroll
    for (int mf = 0; mf < 4; mf++)
      af[mf] = *(const bf16x8*)(smem + (wr * 64 + mf * 16 + (l & 15)) * 64 + ((l >> 4) << 4));
#pragma unroll
    for (int nf = 0; nf < 4; nf++)
      bf[nf] = *(const bf16x8*)(smem + 8192 + (wc * 64 + nf * 16 + (l & 15)) * 64 + ((l >> 4) << 4));
#pragma unroll
    for (int mf = 0; mf < 4; mf++)
#pragma unroll
      for (int nf = 0; nf < 4; nf++)
        acc[mf][nf] = __builtin_amdgcn_mfma_f32_16x16x32_bf16(af[mf], bf[nf], acc[mf][nf], 0, 0, 0);
    __syncthreads();
  }

  if (z == 0) {
#pragma unroll
    for (int mf = 0; mf < 4; mf++)
#pragma unroll
      for (int nf = 0; nf < 4; nf++)
#pragma unroll
        for (int i = 0; i < 4; i++) {
          int m = mbase + wr * 64 + mf * 16 + (l >> 4) * 4 + i;
          int n = nbase + wc * 64 + nf * 16 + (l & 15);
          float v = (acc[mf][nf][i] + bias[n]) * scale;
          int b = m >> 11, s = m & 2047;
          int h = n >> 8, d = n & 255;
          Qg[((size_t)(b * H_ + h) * S_ + s) * C_ + d] = f2bf(v);
        }
  } else {
    short* T = (short*)smem;   // [128][136]
#pragma unroll
    for (int mf = 0; mf < 4; mf++)
#pragma unroll
      for (int nf = 0; nf < 4; nf++)
#pragma unroll
        for (int i = 0; i < 4; i++) {
          int ml = wr * 64 + mf * 16 + (l >> 4) * 4 + i;
          int nl = wc * 64 + nf * 16 + (l & 15);
          float v = (acc[mf][nf][i] + bias[nbase + nl]) * scale;
          T[ml * 136 + nl] = f2bf(v);
        }
    __syncthreads();
    int b = mbase >> 11, s0 = mbase & 2047;
    int h = nbase >> 8;
    int kt0e = s0 >> 5;
    char* hb = (z == 1 ? Kpk : Vpk) + ((size_t)(b * H_ + h) << 20);
    if (z == 1) {
#pragma unroll
      for (int i2 = 0; i2 < 8; i2++) {
        int sid = tid * 8 + i2;
        int kt_l = sid >> 9, rem = sid & 511;
        int ksl = rem >> 6, lane2 = rem & 63;
        int tok = kt_l * 32 + (lane2 & 31);
        int dl = ksl * 16 + ((lane2 >> 5) << 3);
        bf16x8 v = *(const bf16x8*)&T[tok * 136 + dl];
        int ksg = ((nbase & 255) >> 4) + ksl;
        *(bf16x8*)(hb + ((size_t)(kt0e + kt_l) << 14) + ((ksg * 64 + lane2) << 4)) = v;
      }
    } else {
#pragma unroll
      for (int i2 = 0; i2 < 8; i2++) {
        int sid = tid * 8 + i2;
        int kt_l = sid >> 9, rem = sid & 511;
        int dtl = rem >> 7, kb = (rem >> 6) & 1, lane2 = rem & 63;
        int dl = dtl * 32 + (lane2 & 31);
        int k0 = kt_l * 32 + kb * 16 + ((lane2 >> 5) << 3);
        bf16x8 pk;
#pragma unroll
        for (int j = 0; j < 8; j++) pk[j] = T[(k0 + j) * 136 + dl];
        int dtg = ((nbase & 255) >> 5) + dtl;
        *(bf16x8*)(hb + ((size_t)(kt0e + kt_l) << 14) + (((dtg * 2 + kb) * 64 + lane2) << 4)) = pk;
      }
    }
  }
}

// ---------------- out-proj split-K GEMM (z = K-chunk of 512) ----------------
__global__ void __launch_bounds__(256, 2) gemm_out(
    const short* __restrict__ A, const short* __restrict__ Bt,
    float* __restrict__ out, int M, int N, int K) {
  __shared__ char smem[36864];
  const int tid = threadIdx.x;
  const int l = tid & 63;
  const int w = tid >> 6;
  const int wr = w >> 1, wc = w & 1;
  const int mbase = blockIdx.y * 128;
  const int nbase = blockIdx.x * 128;

  const f32x4 fzero = {0.f, 0.f, 0.f, 0.f};
  f32x4 acc[4][4];
#pragma unroll
  for (int i = 0; i < 4; i++)
#pragma unroll
    for (int j = 0; j < 4; j++) acc[i][j] = fzero;

  const int kt0 = blockIdx.z * 16;
  for (int kt = kt0; kt < kt0 + 16; ++kt) {
#pragma unroll
    for (int c = 0; c < 2; c++) {
      int row = c * 64 + w * 16 + (l >> 2);
      const short* ga = A + (size_t)(mbase + row) * K + kt * 32 + (l & 3) * 8;
      gld16(ga, smem + (c * 4 + w) * 1024);
      const short* gb = Bt + (size_t)(nbase + row) * K + kt * 32 + (l & 3) * 8;
      gld16(gb, smem + 8192 + (c * 4 + w) * 1024);
    }
    __syncthreads();
    bf16x8 af[4], bf[4];
#pragma unroll
    for (int mf = 0; mf < 4; mf++)
      af[mf] = *(const bf16x8*)(smem + (wr * 64 + mf * 16 + (l & 15)) * 64 + ((l >> 4) << 4));
#pragma unroll
    for (int nf = 0; nf < 4; nf++)
      bf[nf] = *(const bf16x8*)(smem + 8192 + (wc * 64 + nf * 16 + (l & 15)) * 64 + ((l >> 4) << 4));
#pragma unroll
    for (int mf = 0; mf < 4; mf++)
#pragma unroll
      for (int nf = 0; nf < 4; nf++)
        acc[mf][nf] = __builtin_amdgcn_mfma_f32_16x16x32_bf16(af[mf], bf[nf], acc[mf][nf], 0, 0, 0);
    __syncthreads();
  }

  float* pout = out + (size_t)blockIdx.z * M * N;
#pragma unroll
  for (int mf = 0; mf < 4; mf++)
#pragma unroll
    for (int nf = 0; nf < 4; nf++)
#pragma unroll
      for (int i = 0; i < 4; i++) {
        int m = mbase + wr * 64 + mf * 16 + (l >> 4) * 4 + i;
        int n = nbase + wc * 64 + nf * 16 + (l & 15);
        pout[(size_t)m * N + n] = acc[mf][nf][i];
      }
}

// ---------------- reduce 4 split-K partials + bias -> fp32 out ---------------
__global__ void reduce4(const float* __restrict__ part, const float* __restrict__ bias,
                        float* __restrict__ out) {
  const int MN = 8192 * 256;
  int i = (blockIdx.x * 256 + threadIdx.x) * 4;
  if (i >= MN) return;
  float4 a = *(const float4*)(part + i);
  float4 b = *(const float4*)(part + MN + i);
  float4 c = *(const float4*)(part + 2 * MN + i);
  float4 d = *(const float4*)(part + 3 * MN + i);
  float4 bs = *(const float4*)(bias + (i & 255));
  float4 r;
  r.x = a.x + b.x + c.x + d.x + bs.x;
  r.y = a.y + b.y + c.y + d.y + bs.y;
  r.z = a.z + b.z + c.z + d.z + bs.z;
  r.w = a.w + b.w + c.w + d.w + bs.w;
  *(float4*)(out + i) = r;
}

// ---------------- flash attention (R11-exact: 4 waves, packed K/V, linear LDS)
// grid 512 = 2 blocks/CU (64KB LDS), XCD-chunked; 2 waves/SIMD.
// Wave owns 32 q-rows; swapped QK^T (mfma(K,Q)) + T12 pack; no-max softmax
// (Q pre-scaled by 0.25*log2e). Packed K/V -> linear staging, lane-linear
// conflict-free reads. Reg budget: o 128 AGPR + arch ~124 <= 128 -> no spill.
__global__ void __launch_bounds__(256, 2) attn_k(
    const short* __restrict__ Qg, const char* __restrict__ Kpk,
    const char* __restrict__ Vpk, short* __restrict__ Ag) {
  __shared__ char smem[65536];
  const int tid = threadIdx.x, l = tid & 63, w = tid >> 6;   // w = 0..3
  const int hi = l >> 5;
  const int lq = l & 31;

  const int orig = (blockIdx.x & 7) * 64 + (blockIdx.x >> 3);  // bijective XCD chunk
  const int head = orig >> 4;
  const int qbase = (orig & 15) * 128 + w * 32;

  // Q fragments (B-operand): lane col q = lq, elem j <-> d = ks*16 + hi*8 + j
  bf16x8 qf[16];
  {
    const short* qb = Qg + ((size_t)head * S_ + qbase + lq) * C_;
#pragma unroll
    for (int ks = 0; ks < 16; ks++) {
      qf[ks] = *(const bf16x8*)(qb + ks * 16 + hi * 8);
      asm volatile("" : "+v"(qf[ks]));  // materialize pre-loop
    }
  }

  f32x16 o[8];
#pragma unroll
  for (int dt = 0; dt < 8; dt++)
#pragma unroll
    for (int r = 0; r < 16; r++) o[dt][r] = 0.0f;
  float lrun = 0.0f;

  const char* kpH = Kpk + ((size_t)head << 20);
  const char* vpH = Vpk + ((size_t)head << 20);
  const int vo = tid << 4;        // linear 16B offset, same for src and dest
  const int lo = l << 4;          // lane-linear LDS read offset

  // STAGE tile t into buffer t&1: 8 linear gld16 per thread (4 K + 4 V)
  auto STAGE = [&](int t) {
    char* Kd = smem + (t & 1) * 32768;
    char* Vd = Kd + 16384;
    const char* kq = kpH + ((size_t)t << 14);
    const char* vq = vpH + ((size_t)t << 14);
#pragma unroll
    for (int c = 0; c < 4; c++)
      gld16(kq + c * 4096 + vo, Kd + c * 4096 + vo);
#pragma unroll
    for (int c = 0; c < 4; c++)
      gld16(vq + c * 4096 + vo, Vd + c * 4096 + vo);
  };

  // per-tile compute: QK^T -> exp2 -> T12 pack -> PV (all fragment reads linear)
  auto CALC = [&](int t) {
    const char* Ks = smem + (t & 1) * 32768;
    const char* Vs = Ks + 16384;
    f32x16 st;
#pragma unroll
    for (int r = 0; r < 16; r++) st[r] = 0.0f;
#pragma unroll
    for (int ks = 0; ks < 16; ks++) {
      bf16x8 kf = *(const bf16x8*)(Ks + ks * 1024 + lo);
      st = __builtin_amdgcn_mfma_f32_32x32x16_bf16(kf, qf[ks], st, 0, 0, 0);
    }
#pragma unroll
    for (int r = 0; r < 16; r++) st[r] = exp2f(st[r]);
    {
      float t0 = (st[0] + st[1]) + (st[2] + st[3]);
      float t1 = (st[4] + st[5]) + (st[6] + st[7]);
      float t2 = (st[8] + st[9]) + (st[10] + st[11]);
      float t3 = (st[12] + st[13]) + (st[14] + st[15]);
      lrun += (t0 + t1) + (t2 + t3);
    }
    {
      int a0 = cvtpk(st[0], st[1]), a1 = cvtpk(st[2], st[3]);
      int a2 = cvtpk(st[4], st[5]), a3 = cvtpk(st[6], st[7]);
      auto s0p = __builtin_amdgcn_permlane32_swap(a0, a2, false, false);
      auto s1p = __builtin_amdgcn_permlane32_swap(a1, a3, false, false);
      bf16x8 pf0 = pack4(s0p[0], s1p[0], s0p[1], s1p[1]);  // k 0..15
#pragma unroll
      for (int dt = 0; dt < 8; dt++) {
        bf16x8 v0 = *(const bf16x8*)(Vs + (dt * 2) * 1024 + lo);
        o[dt] = __builtin_amdgcn_mfma_f32_32x32x16_bf16(v0, pf0, o[dt], 0, 0, 0);
      }
    }
    {
      int a4 = cvtpk(st[8], st[9]),   a5 = cvtpk(st[10], st[11]);
      int a6 = cvtpk(st[12], st[13]), a7 = cvtpk(st[14], st[15]);
      auto s2p = __builtin_amdgcn_permlane32_swap(a4, a6, false, false);
      auto s3p = __builtin_amdgcn_permlane32_swap(a5, a7, false, false);
      bf16x8 pf1 = pack4(s2p[0], s3p[0], s2p[1], s3p[1]);  // k 16..31
#pragma unroll
      for (int dt = 0; dt < 8; dt++) {
        bf16x8 v1 = *(const bf16x8*)(Vs + (dt * 2 + 1) * 1024 + lo);
        o[dt] = __builtin_amdgcn_mfma_f32_32x32x16_bf16(v1, pf1, o[dt], 0, 0, 0);
      }
    }
  };

  STAGE(0);

#pragma unroll 1
  for (int t = 0; t < 64; ++t) {
    if (t < 63) {
      STAGE(t + 1);
      asm volatile("s_waitcnt vmcnt(8)" ::: "memory");  // tile t landed; t+1 in flight
    } else {
      asm volatile("s_waitcnt vmcnt(0)" ::: "memory");
    }
    __builtin_amdgcn_s_barrier();   // publish tile t
    CALC(t);
    asm volatile("" ::: "memory");  // pin LDS reads before barrier
    __builtin_amdgcn_s_barrier();   // buf t&1 free for restage at t+1
  }

  // ---- epilogue: finish row sum, normalize, O^T -> LDS (swizzled) -> store
  float lsum = lrun + __shfl_xor(lrun, 32);
  float inv = 1.0f / lsum;
  char* ob = smem + w * 16384;  // per-wave 32 q-rows x 512B
#pragma unroll
  for (int dt = 0; dt < 8; dt++) {
#pragma unroll
    for (int m = 0; m < 4; m++) {
      int lo32 = cvtpk(o[dt][4 * m + 0] * inv, o[dt][4 * m + 1] * inv);
      int hi32 = cvtpk(o[dt][4 * m + 2] * inv, o[dt][4 * m + 3] * inv);
      int cs = (dt * 4 + m) ^ lq;
      int* p = (int*)(ob + lq * 512 + cs * 16 + hi * 8);
      p[0] = lo32; p[1] = hi32;
    }
  }
  int bb = head >> 3, hh = head & 7;
#pragma unroll
  for (int pi = 0; pi < 16; pi++) {
    int qr = pi * 2 + hi;
    bf16x8 v = *(const bf16x8*)(ob + qr * 512 + ((lq ^ qr) << 4));
    size_t g = ((size_t)(bb * S_ + qbase + qr) * (H_ * C_)) + hh * C_ + lq * 8;
    *(bf16x8*)(Ag + g) = v;
  }
}

// ---------------- launch ----------------------------------------------------
extern "C" void kernel_launch(void* const* d_in, const int* in_sizes, int n_in,
                              void* d_out, int out_size, void* d_ws, size_t ws_size,
                              hipStream_t stream) {
  const float* x  = (const float*)d_in[0];
  const float* Wq = (const float*)d_in[1];
  const float* bq = (const float*)d_in[2];
  const float* Wk = (const float*)d_in[3];
  const float* bk = (const float*)d_in[4];
  const float* Wv = (const float*)d_in[5];
  const float* bv = (const float*)d_in[6];
  const float* Wo = (const float*)d_in[7];
  const float* bo = (const float*)d_in[8];

  char* ws = (char*)d_ws;
  short* xb  = (short*)(ws);               //  4 MB
  short* WqT = (short*)(ws + 4194304);     //  1 MB
  short* WkT = (short*)(ws + 5242880);
  short* WvT = (short*)(ws + 6291456);
  short* WoT = (short*)(ws + 7340032);
  short* Qg  = (short*)(ws + 8388608);     // 32 MB (B,H,S,C) row-major
  char*  Kpk = (char*)(ws + 41943040);     // 32 MB packed-K; reused as f32 partials
  char*  Vpk = (char*)(ws + 75497472);     // 32 MB packed-V
  short* Ag  = (short*)(ws + 109051904);   // 32 MB (B,S,H*C)

  prep_k<<<3072, 256, 0, stream>>>(x, xb, Wq, Wk, Wv, Wo, WqT, WkT, WvT, WoT);
  gemm_qkv<<<dim3(16, 64, 3), 256, 0, stream>>>(xb, WqT, WkT, WvT, bq, bk, bv,
                                                Qg, Kpk, Vpk);
  attn_k<<<512, 256, 0, stream>>>(Qg, Kpk, Vpk, Ag);
  gemm_out<<<dim3(2, 64, 4), 256, 0, stream>>>(Ag, WoT, (float*)Kpk, 8192, 256, 2048);
  reduce4<<<2048, 256, 0, stream>>>((const float*)Kpk, bo, (float*)d_out);
}

// Round 15
// 223.738 us; speedup vs baseline: 1.1169x; 1.0328x over previous
//
#include <hip/hip_runtime.h>
#include <stdint.h>
#include <math.h>

#define B_ 4
#define S_ 2048
#define C_ 256
#define H_ 8

typedef short bf16x8 __attribute__((ext_vector_type(8)));
typedef float f32x4 __attribute__((ext_vector_type(4)));
typedef float f32x16 __attribute__((ext_vector_type(16)));

static __device__ __forceinline__ short f2bf(float f) {
  uint32_t u = __float_as_uint(f);
  u = (u + 0x7fffu + ((u >> 16) & 1u)) >> 16;
  return (short)u;
}

static __device__ __forceinline__ int cvtpk(float lo, float hi) {
  int r;
  asm("v_cvt_pk_bf16_f32 %0, %1, %2" : "=v"(r) : "v"(lo), "v"(hi));
  return r;
}

static __device__ __forceinline__ bf16x8 pack4(int a, int b, int c, int d) {
  union { int i[4]; bf16x8 v; } u;
  u.i[0] = a; u.i[1] = b; u.i[2] = c; u.i[3] = d;
  return u.v;
}

static __device__ __forceinline__ void gld16(const void* g, void* l) {
  __builtin_amdgcn_global_load_lds(
      (const __attribute__((address_space(1))) uint32_t*)g,
      (__attribute__((address_space(3))) uint32_t*)l, 16, 0, 0);
}

// ---------------- fused prep: x->bf16 cvt (1024 blocks) + 4x weight transpose
__global__ void prep_k(const float* __restrict__ x, short* __restrict__ xb,
                       const float* __restrict__ Wq, const float* __restrict__ Wk,
                       const float* __restrict__ Wv, const float* __restrict__ Wo,
                       short* __restrict__ WqT, short* __restrict__ WkT,
                       short* __restrict__ WvT, short* __restrict__ WoT) {
  int bid = blockIdx.x;
  if (bid < 1024) {
    int i = (bid * 256 + threadIdx.x) * 8;
    float4 a = *(const float4*)(x + i);
    float4 b = *(const float4*)(x + i + 4);
    bf16x8 r;
    r[0] = f2bf(a.x); r[1] = f2bf(a.y); r[2] = f2bf(a.z); r[3] = f2bf(a.w);
    r[4] = f2bf(b.x); r[5] = f2bf(b.y); r[6] = f2bf(b.z); r[7] = f2bf(b.w);
    *(bf16x8*)(xb + i) = r;
    return;
  }
  __shared__ float t[32][33];
  int tbid = bid - 1024;           // 0..2047
  int which = tbid >> 9, rem = tbid & 511;
  const float* in; short* outp; int R, Cc, bx, by;
  if (which < 3) {
    R = 256; Cc = 2048; bx = rem & 63; by = rem >> 6;
    in = which == 0 ? Wq : (which == 1 ? Wk : Wv);
    outp = which == 0 ? WqT : (which == 1 ? WkT : WvT);
  } else {
    R = 2048; Cc = 256; bx = rem & 7; by = rem >> 3;
    in = Wo; outp = WoT;
  }
  int cb = bx * 32, rb = by * 32;
  int tr = threadIdx.x >> 5;
  int tc = threadIdx.x & 31;
#pragma unroll
  for (int i = 0; i < 4; i++)
    t[tr + i * 8][tc] = in[(size_t)(rb + tr + i * 8) * Cc + cb + tc];
  __syncthreads();
#pragma unroll
  for (int i = 0; i < 4; i++)
    outp[(size_t)(cb + tr + i * 8) * R + rb + tc] = f2bf(t[tc][tr + i * 8]);
}

// ---------------- fused QKV GEMM: one launch, z = {0:Q, 1:K, 2:V} ------------
// A (8192x256 bf16) * W^T (2048x256 bf16) + bias, K-loop double-buffered with
// counted vmcnt (no full drain before barrier). Epilogues:
// z=0: Q row-major (B,H,S,C), val=(acc+bias)*scq (scq folds log2e)
// z=1: K packed-fragment tiles (1MB/head), val=(acc+bias)*0.25
// z=2: V packed-fragment tiles, val=acc+bias
__global__ void __launch_bounds__(256, 2) gemm_qkv(
    const short* __restrict__ A,
    const short* __restrict__ WqT, const short* __restrict__ WkT,
    const short* __restrict__ WvT,
    const float* __restrict__ bq, const float* __restrict__ bk,
    const float* __restrict__ bv,
    short* __restrict__ Qg, char* __restrict__ Kpk, char* __restrict__ Vpk) {
  __shared__ char smem[36864];
  const int tid = threadIdx.x;
  const int l = tid & 63;
  const int w = tid >> 6;
  const int wr = w >> 1, wc = w & 1;
  const int mbase = blockIdx.y * 128;
  const int nbase = blockIdx.x * 128;
  const int z = blockIdx.z;

  const short* Bt = z == 0 ? WqT : (z == 1 ? WkT : WvT);
  const float* bias = z == 0 ? bq : (z == 1 ? bk : bv);
  const float scale = z == 0 ? 0.25f * 1.44269504088896f : (z == 1 ? 0.25f : 1.0f);

  const f32x4 fzero = {0.f, 0.f, 0.f, 0.f};
  f32x4 acc[4][4];
#pragma unroll
  for (int i = 0; i < 4; i++)
#pragma unroll
    for (int j = 0; j < 4; j++) acc[i][j] = fzero;

  // stage K-iter kt into buffer kt&1 (A 8KB + B 8KB); 4 gld16/thread
  auto STAGE = [&](int kt) {
    char* Ad = smem + (kt & 1) * 16384;
    char* Bd = Ad + 8192;
#pragma unroll
    for (int c = 0; c < 2; c++) {
      int row = c * 64 + w * 16 + (l >> 2);
      const short* ga = A + (size_t)(mbase + row) * 256 + kt * 32 + (l & 3) * 8;
      gld16(ga, Ad + (c * 4 + w) * 1024);
      const short* gb = Bt + (size_t)(nbase + row) * 256 + kt * 32 + (l & 3) * 8;
      gld16(gb, Bd + (c * 4 + w) * 1024);
    }
  };

  STAGE(0);
#pragma unroll 1
  for (int kt = 0; kt < 8; ++kt) {
    if (kt < 7) {
      STAGE(kt + 1);
      asm volatile("s_waitcnt vmcnt(4)" ::: "memory");  // iter kt landed; kt+1 in flight
    } else {
      asm volatile("s_waitcnt vmcnt(0)" ::: "memory");
    }
    __builtin_amdgcn_s_barrier();
    const char* Ab = smem + (kt & 1) * 16384;
    const char* Bb = Ab + 8192;
    bf16x8 af[4], bf[4];
#pragma unroll
    for (int mf = 0; mf < 4; mf++)
      af[mf] = *(const bf16x8*)(Ab + (wr * 64 + mf * 16 + (l & 15)) * 64 + ((l >> 4) << 4));
#pragma unroll
    for (int nf = 0; nf < 4; nf++)
      bf[nf] = *(const bf16x8*)(Bb + (wc * 64 + nf * 16 + (l & 15)) * 64 + ((l >> 4) << 4));
#pragma unroll
    for (int mf = 0; mf < 4; mf++)
#pragma unroll
      for (int nf = 0; nf < 4; nf++)
        acc[mf][nf] = __builtin_amdgcn_mfma_f32_16x16x32_bf16(af[mf], bf[nf], acc[mf][nf], 0, 0, 0);
    asm volatile("" ::: "memory");  // pin LDS reads before barrier
    __builtin_amdgcn_s_barrier();   // buf kt&1 free for restage
  }

  if (z == 0) {
#pragma unroll
    for (int mf = 0; mf < 4; mf++)
#pragma unroll
      for (int nf = 0; nf < 4; nf++)
#pragma unroll
        for (int i = 0; i < 4; i++) {
          int m = mbase + wr * 64 + mf * 16 + (l >> 4) * 4 + i;
          int n = nbase + wc * 64 + nf * 16 + (l & 15);
          float v = (acc[mf][nf][i] + bias[n]) * scale;
          int b = m >> 11, s = m & 2047;
          int h = n >> 8, d = n & 255;
          Qg[((size_t)(b * H_ + h) * S_ + s) * C_ + d] = f2bf(v);
        }
  } else {
    short* T = (short*)smem;   // [128][136] = 34 KB (loop done; whole smem free)
#pragma unroll
    for (int mf = 0; mf < 4; mf++)
#pragma unroll
      for (int nf = 0; nf < 4; nf++)
#pragma unroll
        for (int i = 0; i < 4; i++) {
          int ml = wr * 64 + mf * 16 + (l >> 4) * 4 + i;
          int nl = wc * 64 + nf * 16 + (l & 15);
          float v = (acc[mf][nf][i] + bias[nbase + nl]) * scale;
          T[ml * 136 + nl] = f2bf(v);
        }
    __syncthreads();
    int b = mbase >> 11, s0 = mbase & 2047;
    int h = nbase >> 8;
    int kt0e = s0 >> 5;
    char* hb = (z == 1 ? Kpk : Vpk) + ((size_t)(b * H_ + h) << 20);
    if (z == 1) {
#pragma unroll
      for (int i2 = 0; i2 < 8; i2++) {
        int sid = tid * 8 + i2;
        int kt_l = sid >> 9, rem = sid & 511;
        int ksl = rem >> 6, lane2 = rem & 63;
        int tok = kt_l * 32 + (lane2 & 31);
        int dl = ksl * 16 + ((lane2 >> 5) << 3);
        bf16x8 v = *(const bf16x8*)&T[tok * 136 + dl];
        int ksg = ((nbase & 255) >> 4) + ksl;
        *(bf16x8*)(hb + ((size_t)(kt0e + kt_l) << 14) + ((ksg * 64 + lane2) << 4)) = v;
      }
    } else {
#pragma unroll
      for (int i2 = 0; i2 < 8; i2++) {
        int sid = tid * 8 + i2;
        int kt_l = sid >> 9, rem = sid & 511;
        int dtl = rem >> 7, kb = (rem >> 6) & 1, lane2 = rem & 63;
        int dl = dtl * 32 + (lane2 & 31);
        int k0 = kt_l * 32 + kb * 16 + ((lane2 >> 5) << 3);
        bf16x8 pk;
#pragma unroll
        for (int j = 0; j < 8; j++) pk[j] = T[(k0 + j) * 136 + dl];
        int dtg = ((nbase & 255) >> 5) + dtl;
        *(bf16x8*)(hb + ((size_t)(kt0e + kt_l) << 14) + (((dtg * 2 + kb) * 64 + lane2) << 4)) = pk;
      }
    }
  }
}

// ---------------- out-proj split-K GEMM (z = K-chunk of 512), pipelined ------
__global__ void __launch_bounds__(256, 2) gemm_out(
    const short* __restrict__ A, const short* __restrict__ Bt,
    float* __restrict__ out, int M, int N, int K) {
  __shared__ char smem[32768];
  const int tid = threadIdx.x;
  const int l = tid & 63;
  const int w = tid >> 6;
  const int wr = w >> 1, wc = w & 1;
  const int mbase = blockIdx.y * 128;
  const int nbase = blockIdx.x * 128;

  const f32x4 fzero = {0.f, 0.f, 0.f, 0.f};
  f32x4 acc[4][4];
#pragma unroll
  for (int i = 0; i < 4; i++)
#pragma unroll
    for (int j = 0; j < 4; j++) acc[i][j] = fzero;

  const int kt0 = blockIdx.z * 16;

  auto STAGE = [&](int kt) {   // kt relative 0..15
    char* Ad = smem + (kt & 1) * 16384;
    char* Bd = Ad + 8192;
#pragma unroll
    for (int c = 0; c < 2; c++) {
      int row = c * 64 + w * 16 + (l >> 2);
      const short* ga = A + (size_t)(mbase + row) * K + (kt0 + kt) * 32 + (l & 3) * 8;
      gld16(ga, Ad + (c * 4 + w) * 1024);
      const short* gb = Bt + (size_t)(nbase + row) * K + (kt0 + kt) * 32 + (l & 3) * 8;
      gld16(gb, Bd + (c * 4 + w) * 1024);
    }
  };

  STAGE(0);
#pragma unroll 1
  for (int kt = 0; kt < 16; ++kt) {
    if (kt < 15) {
      STAGE(kt + 1);
      asm volatile("s_waitcnt vmcnt(4)" ::: "memory");
    } else {
      asm volatile("s_waitcnt vmcnt(0)" ::: "memory");
    }
    __builtin_amdgcn_s_barrier();
    const char* Ab = smem + (kt & 1) * 16384;
    const char* Bb = Ab + 8192;
    bf16x8 af[4], bf[4];
#pragma unroll
    for (int mf = 0; mf < 4; mf++)
      af[mf] = *(const bf16x8*)(Ab + (wr * 64 + mf * 16 + (l & 15)) * 64 + ((l >> 4) << 4));
#pragma unroll
    for (int nf = 0; nf < 4; nf++)
      bf[nf] = *(const bf16x8*)(Bb + (wc * 64 + nf * 16 + (l & 15)) * 64 + ((l >> 4) << 4));
#pragma unroll
    for (int mf = 0; mf < 4; mf++)
#pragma unroll
      for (int nf = 0; nf < 4; nf++)
        acc[mf][nf] = __builtin_amdgcn_mfma_f32_16x16x32_bf16(af[mf], bf[nf], acc[mf][nf], 0, 0, 0);
    asm volatile("" ::: "memory");
    __builtin_amdgcn_s_barrier();
  }

  float* pout = out + (size_t)blockIdx.z * M * N;
#pragma unroll
  for (int mf = 0; mf < 4; mf++)
#pragma unroll
    for (int nf = 0; nf < 4; nf++)
#pragma unroll
      for (int i = 0; i < 4; i++) {
        int m = mbase + wr * 64 + mf * 16 + (l >> 4) * 4 + i;
        int n = nbase + wc * 64 + nf * 16 + (l & 15);
        pout[(size_t)m * N + n] = acc[mf][nf][i];
      }
}

// ---------------- reduce 4 split-K partials + bias -> fp32 out ---------------
__global__ void reduce4(const float* __restrict__ part, const float* __restrict__ bias,
                        float* __restrict__ out) {
  const int MN = 8192 * 256;
  int i = (blockIdx.x * 256 + threadIdx.x) * 4;
  if (i >= MN) return;
  float4 a = *(const float4*)(part + i);
  float4 b = *(const float4*)(part + MN + i);
  float4 c = *(const float4*)(part + 2 * MN + i);
  float4 d = *(const float4*)(part + 3 * MN + i);
  float4 bs = *(const float4*)(bias + (i & 255));
  float4 r;
  r.x = a.x + b.x + c.x + d.x + bs.x;
  r.y = a.y + b.y + c.y + d.y + bs.y;
  r.z = a.z + b.z + c.z + d.z + bs.z;
  r.w = a.w + b.w + c.w + d.w + bs.w;
  *(float4*)(out + i) = r;
}

// ---------------- flash attention (R11-exact: 4 waves, packed K/V, linear LDS)
// grid 512 = 2 blocks/CU (64KB LDS), XCD-chunked; 2 waves/SIMD.
// Wave owns 32 q-rows; swapped QK^T (mfma(K,Q)) + T12 pack; no-max softmax
// (Q pre-scaled by 0.25*log2e). Packed K/V -> linear staging, lane-linear
// conflict-free reads. Reg budget: o 128 AGPR + arch ~124 <= 128 -> no spill.
__global__ void __launch_bounds__(256, 2) attn_k(
    const short* __restrict__ Qg, const char* __restrict__ Kpk,
    const char* __restrict__ Vpk, short* __restrict__ Ag) {
  __shared__ char smem[65536];
  const int tid = threadIdx.x, l = tid & 63, w = tid >> 6;   // w = 0..3
  const int hi = l >> 5;
  const int lq = l & 31;

  const int orig = (blockIdx.x & 7) * 64 + (blockIdx.x >> 3);  // bijective XCD chunk
  const int head = orig >> 4;
  const int qbase = (orig & 15) * 128 + w * 32;

  // Q fragments (B-operand): lane col q = lq, elem j <-> d = ks*16 + hi*8 + j
  bf16x8 qf[16];
  {
    const short* qb = Qg + ((size_t)head * S_ + qbase + lq) * C_;
#pragma unroll
    for (int ks = 0; ks < 16; ks++) {
      qf[ks] = *(const bf16x8*)(qb + ks * 16 + hi * 8);
      asm volatile("" : "+v"(qf[ks]));  // materialize pre-loop
    }
  }

  f32x16 o[8];
#pragma unroll
  for (int dt = 0; dt < 8; dt++)
#pragma unroll
    for (int r = 0; r < 16; r++) o[dt][r] = 0.0f;
  float lrun = 0.0f;

  const char* kpH = Kpk + ((size_t)head << 20);
  const char* vpH = Vpk + ((size_t)head << 20);
  const int vo = tid << 4;        // linear 16B offset, same for src and dest
  const int lo = l << 4;          // lane-linear LDS read offset

  // STAGE tile t into buffer t&1: 8 linear gld16 per thread (4 K + 4 V)
  auto STAGE = [&](int t) {
    char* Kd = smem + (t & 1) * 32768;
    char* Vd = Kd + 16384;
    const char* kq = kpH + ((size_t)t << 14);
    const char* vq = vpH + ((size_t)t << 14);
#pragma unroll
    for (int c = 0; c < 4; c++)
      gld16(kq + c * 4096 + vo, Kd + c * 4096 + vo);
#pragma unroll
    for (int c = 0; c < 4; c++)
      gld16(vq + c * 4096 + vo, Vd + c * 4096 + vo);
  };

  // per-tile compute: QK^T -> exp2 -> T12 pack -> PV (all fragment reads linear)
  auto CALC = [&](int t) {
    const char* Ks = smem + (t & 1) * 32768;
    const char* Vs = Ks + 16384;
    f32x16 st;
#pragma unroll
    for (int r = 0; r < 16; r++) st[r] = 0.0f;
#pragma unroll
    for (int ks = 0; ks < 16; ks++) {
      bf16x8 kf = *(const bf16x8*)(Ks + ks * 1024 + lo);
      st = __builtin_amdgcn_mfma_f32_32x32x16_bf16(kf, qf[ks], st, 0, 0, 0);
    }
#pragma unroll
    for (int r = 0; r < 16; r++) st[r] = exp2f(st[r]);
    {
      float t0 = (st[0] + st[1]) + (st[2] + st[3]);
      float t1 = (st[4] + st[5]) + (st[6] + st[7]);
      float t2 = (st[8] + st[9]) + (st[10] + st[11]);
      float t3 = (st[12] + st[13]) + (st[14] + st[15]);
      lrun += (t0 + t1) + (t2 + t3);
    }
    {
      int a0 = cvtpk(st[0], st[1]), a1 = cvtpk(st[2], st[3]);
      int a2 = cvtpk(st[4], st[5]), a3 = cvtpk(st[6], st[7]);
      auto s0p = __builtin_amdgcn_permlane32_swap(a0, a2, false, false);
      auto s1p = __builtin_amdgcn_permlane32_swap(a1, a3, false, false);
      bf16x8 pf0 = pack4(s0p[0], s1p[0], s0p[1], s1p[1]);  // k 0..15
#pragma unroll
      for (int dt = 0; dt < 8; dt++) {
        bf16x8 v0 = *(const bf16x8*)(Vs + (dt * 2) * 1024 + lo);
        o[dt] = __builtin_amdgcn_mfma_f32_32x32x16_bf16(v0, pf0, o[dt], 0, 0, 0);
      }
    }
    {
      int a4 = cvtpk(st[8], st[9]),   a5 = cvtpk(st[10], st[11]);
      int a6 = cvtpk(st[12], st[13]), a7 = cvtpk(st[14], st[15]);
      auto s2p = __builtin_amdgcn_permlane32_swap(a4, a6, false, false);
      auto s3p = __builtin_amdgcn_permlane32_swap(a5, a7, false, false);
      bf16x8 pf1 = pack4(s2p[0], s3p[0], s2p[1], s3p[1]);  // k 16..31
#pragma unroll
      for (int dt = 0; dt < 8; dt++) {
        bf16x8 v1 = *(const bf16x8*)(Vs + (dt * 2 + 1) * 1024 + lo);
        o[dt] = __builtin_amdgcn_mfma_f32_32x32x16_bf16(v1, pf1, o[dt], 0, 0, 0);
      }
    }
  };

  STAGE(0);

#pragma unroll 1
  for (int t = 0; t < 64; ++t) {
    if (t < 63) {
      STAGE(t + 1);
      asm volatile("s_waitcnt vmcnt(8)" ::: "memory");  // tile t landed; t+1 in flight
    } else {
      asm volatile("s_waitcnt vmcnt(0)" ::: "memory");
    }
    __builtin_amdgcn_s_barrier();   // publish tile t
    CALC(t);
    asm volatile("" ::: "memory");  // pin LDS reads before barrier
    __builtin_amdgcn_s_barrier();   // buf t&1 free for restage at t+1
  }

  // ---- epilogue: finish row sum, normalize, O^T -> LDS (swizzled) -> store
  float lsum = lrun + __shfl_xor(lrun, 32);
  float inv = 1.0f / lsum;
  char* ob = smem + w * 16384;  // per-wave 32 q-rows x 512B
#pragma unroll
  for (int dt = 0; dt < 8; dt++) {
#pragma unroll
    for (int m = 0; m < 4; m++) {
      int lo32 = cvtpk(o[dt][4 * m + 0] * inv, o[dt][4 * m + 1] * inv);
      int hi32 = cvtpk(o[dt][4 * m + 2] * inv, o[dt][4 * m + 3] * inv);
      int cs = (dt * 4 + m) ^ lq;
      int* p = (int*)(ob + lq * 512 + cs * 16 + hi * 8);
      p[0] = lo32; p[1] = hi32;
    }
  }
  int bb = head >> 3, hh = head & 7;
#pragma unroll
  for (int pi = 0; pi < 16; pi++) {
    int qr = pi * 2 + hi;
    bf16x8 v = *(const bf16x8*)(ob + qr * 512 + ((lq ^ qr) << 4));
    size_t g = ((size_t)(bb * S_ + qbase + qr) * (H_ * C_)) + hh * C_ + lq * 8;
    *(bf16x8*)(Ag + g) = v;
  }
}

// ---------------- launch ----------------------------------------------------
extern "C" void kernel_launch(void* const* d_in, const int* in_sizes, int n_in,
                              void* d_out, int out_size, void* d_ws, size_t ws_size,
                              hipStream_t stream) {
  const float* x  = (const float*)d_in[0];
  const float* Wq = (const float*)d_in[1];
  const float* bq = (const float*)d_in[2];
  const float* Wk = (const float*)d_in[3];
  const float* bk = (const float*)d_in[4];
  const float* Wv = (const float*)d_in[5];
  const float* bv = (const float*)d_in[6];
  const float* Wo = (const float*)d_in[7];
  const float* bo = (const float*)d_in[8];

  char* ws = (char*)d_ws;
  short* xb  = (short*)(ws);               //  4 MB
  short* WqT = (short*)(ws + 4194304);     //  1 MB
  short* WkT = (short*)(ws + 5242880);
  short* WvT = (short*)(ws + 6291456);
  short* WoT = (short*)(ws + 7340032);
  short* Qg  = (short*)(ws + 8388608);     // 32 MB (B,H,S,C) row-major
  char*  Kpk = (char*)(ws + 41943040);     // 32 MB packed-K; reused as f32 partials
  char*  Vpk = (char*)(ws + 75497472);     // 32 MB packed-V
  short* Ag  = (short*)(ws + 109051904);   // 32 MB (B,S,H*C)

  prep_k<<<3072, 256, 0, stream>>>(x, xb, Wq, Wk, Wv, Wo, WqT, WkT, WvT, WoT);
  gemm_qkv<<<dim3(16, 64, 3), 256, 0, stream>>>(xb, WqT, WkT, WvT, bq, bk, bv,
                                                Qg, Kpk, Vpk);
  attn_k<<<512, 256, 0, stream>>>(Qg, Kpk, Vpk, Ag);
  gemm_out<<<dim3(2, 64, 4), 256, 0, stream>>>(Ag, WoT, (float*)Kpk, 8192, 256, 2048);
  reduce4<<<2048, 256, 0, stream>>>((const float*)Kpk, bo, (float*)d_out);
}